// Round 1
// baseline (543.509 us; speedup 1.0000x reference)
//
#include <hip/hip_runtime.h>
#include <hip/hip_bf16.h>

namespace {
constexpr int Bv = 8;
constexpr int Nv = 2048;
constexpr int Dv = 256;
constexpr float SCALE = 0.1f;
constexpr float LN_EPS = 1e-6f;
constexpr float NORM_EPS = 1e-12f;
}

__device__ __forceinline__ float wave_sum(float v) {
#pragma unroll
    for (int o = 1; o < 64; o <<= 1) v += __shfl_xor(v, o, 64);
    return v;
}
__device__ __forceinline__ float wave_max(float v) {
#pragma unroll
    for (int o = 1; o < 64; o <<= 1) v = fmaxf(v, __shfl_xor(v, o, 64));
    return v;
}

// ---------------------------------------------------------------------------
// 1) L2-normalize each (b,n) row of x along D. One wave per row.
__global__ __launch_bounds__(256) void k_normalize(const float* __restrict__ x,
                                                   float* __restrict__ xn) {
    const int wave = threadIdx.x >> 6, lane = threadIdx.x & 63;
    const size_t row = (size_t)blockIdx.x * 4 + wave;
    float4 v = ((const float4*)(x + row * Dv))[lane];
    float ss = v.x * v.x + v.y * v.y + v.z * v.z + v.w * v.w;
    ss = wave_sum(ss);
    const float inv = 1.0f / fmaxf(sqrtf(ss), NORM_EPS);
    ((float4*)(xn + row * Dv))[lane] =
        make_float4(v.x * inv, v.y * inv, v.z * inv, v.w * inv);
}

// ---------------------------------------------------------------------------
// 2) S[b] = xn[b] @ xn[b]^T  (TEMP = 1).  64x64 tile per block, 4x4 microtile.
__global__ __launch_bounds__(256) void k_simgemm(const float* __restrict__ xn,
                                                 float* __restrict__ S) {
    __shared__ float As[32][68];
    __shared__ float Bs[32][68];
    const int b = blockIdx.z;
    const int bi = blockIdx.y;
    const int bj = blockIdx.x;
    const float* xb = xn + (size_t)b * Nv * Dv;
    const int t = threadIdx.x;
    const int tx = t & 15, ty = t >> 4;
    float acc[4][4] = {};
    for (int k0 = 0; k0 < Dv; k0 += 32) {
#pragma unroll
        for (int l = 0; l < 2; ++l) {
            const int lin = t + l * 256;     // 0..511 float4 slots
            const int row = lin >> 3;        // 0..63
            const int k4 = (lin & 7) << 2;   // 0..28
            float4 a = *(const float4*)(xb + (size_t)(bi * 64 + row) * Dv + k0 + k4);
            As[k4 + 0][row] = a.x; As[k4 + 1][row] = a.y;
            As[k4 + 2][row] = a.z; As[k4 + 3][row] = a.w;
            float4 bb = *(const float4*)(xb + (size_t)(bj * 64 + row) * Dv + k0 + k4);
            Bs[k4 + 0][row] = bb.x; Bs[k4 + 1][row] = bb.y;
            Bs[k4 + 2][row] = bb.z; Bs[k4 + 3][row] = bb.w;
        }
        __syncthreads();
#pragma unroll
        for (int k = 0; k < 32; ++k) {
            float ar[4], br[4];
            *(float4*)ar = *(const float4*)&As[k][ty * 4];
            *(float4*)br = *(const float4*)&Bs[k][tx * 4];
#pragma unroll
            for (int i = 0; i < 4; ++i)
#pragma unroll
                for (int j = 0; j < 4; ++j)
                    acc[i][j] = fmaf(ar[i], br[j], acc[i][j]);
        }
        __syncthreads();
    }
    float* Sb = S + (size_t)b * Nv * Nv;
#pragma unroll
    for (int i = 0; i < 4; ++i) {
        *(float4*)(Sb + (size_t)(bi * 64 + ty * 4 + i) * Nv + bj * 64 + tx * 4) =
            make_float4(acc[i][0], acc[i][1], acc[i][2], acc[i][3]);
    }
}

// ---------------------------------------------------------------------------
// 3) In-place row softmax over each length-2048 row of S. One block per row.
__global__ __launch_bounds__(256) void k_rowsoftmax(float* __restrict__ S) {
    __shared__ float red[8];
    float* p = S + (size_t)blockIdx.x * Nv;
    const int t = threadIdx.x;
    const int wave = t >> 6, lane = t & 63;
    float v[8];
    *(float4*)&v[0] = ((const float4*)p)[t];
    *(float4*)&v[4] = ((const float4*)p)[t + 256];
    float m = v[0];
#pragma unroll
    for (int i = 1; i < 8; ++i) m = fmaxf(m, v[i]);
    m = wave_max(m);
    if (lane == 0) red[wave] = m;
    __syncthreads();
    m = fmaxf(fmaxf(red[0], red[1]), fmaxf(red[2], red[3]));
    float s = 0.f;
#pragma unroll
    for (int i = 0; i < 8; ++i) { v[i] = expf(v[i] - m); s += v[i]; }
    s = wave_sum(s);
    if (lane == 0) red[4 + wave] = s;
    __syncthreads();
    s = red[4] + red[5] + red[6] + red[7];
    const float inv = 1.0f / s;
#pragma unroll
    for (int i = 0; i < 8; ++i) v[i] *= inv;
    ((float4*)p)[t] = *(const float4*)&v[0];
    ((float4*)p)[t + 256] = *(const float4*)&v[4];
}

// ---------------------------------------------------------------------------
// 4) x_neg[b,r,:] = sum_k (R[b,r,k] + R[b,k,r]) * x[b,k,:]
//    32-row x 256-col tile per block; thread microtile 4x8. Writes into d_out.
__global__ __launch_bounds__(256) void k_gemm2(const float* __restrict__ R,
                                               const float* __restrict__ x,
                                               float* __restrict__ xneg) {
    __shared__ float Ws[32][36];
    __shared__ float xs[32][Dv + 4];
    const int b = blockIdx.y;
    const int bi = blockIdx.x;
    const float* Rb = R + (size_t)b * Nv * Nv;
    const float* xb = x + (size_t)b * Nv * Dv;
    const int t = threadIdx.x;
    const int tc = t & 31, tr = t >> 5;
    const int row = t >> 3;        // 0..31
    const int k4 = (t & 7) << 2;   // 0..28
    float acc[4][8] = {};
    for (int k0 = 0; k0 < Nv; k0 += 32) {
        {   // W part 1: Ws[k][r] = R[bi*32+r][k0+k]   (transposed store)
            float4 a = *(const float4*)(Rb + (size_t)(bi * 32 + row) * Nv + k0 + k4);
            Ws[k4 + 0][row] = a.x; Ws[k4 + 1][row] = a.y;
            Ws[k4 + 2][row] = a.z; Ws[k4 + 3][row] = a.w;
        }
#pragma unroll
        for (int l = 0; l < 8; ++l) {   // x tile: 32 k-rows x 256 d
            const int lin = t + l * 256;
            const int kr = lin >> 6;
            const int d4 = (lin & 63) << 2;
            *(float4*)&xs[kr][d4] = *(const float4*)(xb + (size_t)(k0 + kr) * Dv + d4);
        }
        __syncthreads();
        {   // W part 2: Ws[k][c] += R[k0+k][bi*32+c]  (direct rows, contiguous)
            float4 a = *(const float4*)(Rb + (size_t)(k0 + row) * Nv + bi * 32 + k4);
            float4 cur = *(const float4*)&Ws[row][k4];
            cur.x += a.x; cur.y += a.y; cur.z += a.z; cur.w += a.w;
            *(float4*)&Ws[row][k4] = cur;
        }
        __syncthreads();
#pragma unroll
        for (int k = 0; k < 32; ++k) {
            float w[4], xv[8];
            *(float4*)w = *(const float4*)&Ws[k][tr * 4];
            *(float4*)&xv[0] = *(const float4*)&xs[k][tc * 8];
            *(float4*)&xv[4] = *(const float4*)&xs[k][tc * 8 + 4];
#pragma unroll
            for (int i = 0; i < 4; ++i)
#pragma unroll
                for (int j = 0; j < 8; ++j)
                    acc[i][j] = fmaf(w[i], xv[j], acc[i][j]);
        }
        __syncthreads();
    }
    float* ob = xneg + ((size_t)b * Nv + bi * 32) * Dv;
#pragma unroll
    for (int i = 0; i < 4; ++i) {
        *(float4*)(ob + (size_t)(tr * 4 + i) * Dv + tc * 8) =
            make_float4(acc[i][0], acc[i][1], acc[i][2], acc[i][3]);
        *(float4*)(ob + (size_t)(tr * 4 + i) * Dv + tc * 8 + 4) =
            make_float4(acc[i][4], acc[i][5], acc[i][6], acc[i][7]);
    }
}

// ---------------------------------------------------------------------------
// 5) y = LayerNorm(x - SCALE*x_neg) * gamma + beta. One wave per row, in-place
//    on d_out (which holds x_neg).
__global__ __launch_bounds__(256) void k_final(const float* __restrict__ x,
                                               const float* __restrict__ gamma,
                                               const float* __restrict__ beta,
                                               float* __restrict__ out) {
    const int wave = threadIdx.x >> 6, lane = threadIdx.x & 63;
    const size_t row = (size_t)blockIdx.x * 4 + wave;
    float4 xv = ((const float4*)(x + row * Dv))[lane];
    float4 nv = ((const float4*)(out + row * Dv))[lane];
    const float t0 = xv.x - SCALE * nv.x;
    const float t1 = xv.y - SCALE * nv.y;
    const float t2 = xv.z - SCALE * nv.z;
    const float t3 = xv.w - SCALE * nv.w;
    const float s1 = wave_sum(t0 + t1 + t2 + t3);
    const float s2 = wave_sum(t0 * t0 + t1 * t1 + t2 * t2 + t3 * t3);
    const float mu = s1 * (1.0f / Dv);
    const float var = s2 * (1.0f / Dv) - mu * mu;
    const float rstd = rsqrtf(var + LN_EPS);
    float4 g = ((const float4*)gamma)[lane];
    float4 be = ((const float4*)beta)[lane];
    float4 o;
    o.x = (t0 - mu) * rstd * g.x + be.x;
    o.y = (t1 - mu) * rstd * g.y + be.y;
    o.z = (t2 - mu) * rstd * g.z + be.z;
    o.w = (t3 - mu) * rstd * g.w + be.w;
    ((float4*)(out + row * Dv))[lane] = o;
}

// ---------------------------------------------------------------------------
extern "C" void kernel_launch(void* const* d_in, const int* in_sizes, int n_in,
                              void* d_out, int out_size, void* d_ws, size_t ws_size,
                              hipStream_t stream) {
    const float* x = (const float*)d_in[0];
    const float* gamma = (const float*)d_in[1];
    const float* beta = (const float*)d_in[2];
    float* out = (float*)d_out;
    float* xn = (float*)d_ws;                          // B*N*D f32 = 16.8 MB
    float* S = xn + (size_t)Bv * Nv * Dv;              // B*N*N f32 = 134 MB

    k_normalize<<<(Bv * Nv) / 4, 256, 0, stream>>>(x, xn);
    dim3 gs(Nv / 64, Nv / 64, Bv);
    k_simgemm<<<gs, 256, 0, stream>>>(xn, S);
    k_rowsoftmax<<<Bv * Nv, 256, 0, stream>>>(S);
    dim3 g2(Nv / 32, Bv);
    k_gemm2<<<g2, 256, 0, stream>>>(S, x, out);
    k_final<<<(Bv * Nv) / 4, 256, 0, stream>>>(x, gamma, beta, out);
}

// Round 2
// 133.725 us; speedup vs baseline: 4.0644x; 4.0644x over previous
//
#include <hip/hip_runtime.h>
#include <hip/hip_bf16.h>

namespace {
constexpr int Bv = 8;
constexpr int Nv = 2048;
constexpr int Dv = 256;
constexpr float SCALE = 0.1f;
constexpr float LN_EPS = 1e-6f;
constexpr float NORM_EPS = 1e-12f;
}

typedef unsigned short u16;
typedef __attribute__((ext_vector_type(8))) short short8;
typedef __attribute__((ext_vector_type(4))) float f32x4;
typedef __attribute__((ext_vector_type(8))) unsigned short us8;
typedef __attribute__((ext_vector_type(4))) unsigned short us4;

__device__ __forceinline__ u16 f2bf(float f) {
    union { float f; unsigned u; } v; v.f = f;
    unsigned r = v.u + 0x7fffu + ((v.u >> 16) & 1u);
    return (u16)(r >> 16);
}
__device__ __forceinline__ float bf2f(u16 h) {
    union { unsigned u; float f; } v; v.u = ((unsigned)h) << 16; return v.f;
}
// global -> LDS direct DMA, 16B per lane. lds must be wave-uniform base.
__device__ __forceinline__ void gll16(const void* g, void* l) {
    __builtin_amdgcn_global_load_lds(
        (__attribute__((address_space(1))) void*)(uintptr_t)g,
        (__attribute__((address_space(3))) void*)(uintptr_t)l, 16, 0, 0);
}
__device__ __forceinline__ float wave_sum(float v) {
#pragma unroll
    for (int o = 1; o < 64; o <<= 1) v += __shfl_xor(v, o, 64);
    return v;
}

// ---------------------------------------------------------------------------
// 1) L2-normalize rows -> xn (bf16); also zero lsum.
__global__ __launch_bounds__(256) void k_prep(const float* __restrict__ x,
                                              u16* __restrict__ xn,
                                              float* __restrict__ lsum) {
    const int wave = threadIdx.x >> 6, lane = threadIdx.x & 63;
    const size_t row = (size_t)blockIdx.x * 4 + wave;
    float4 v = ((const float4*)(x + row * Dv))[lane];
    float ss = v.x * v.x + v.y * v.y + v.z * v.z + v.w * v.w;
    ss = wave_sum(ss);
    const float inv = 1.0f / fmaxf(sqrtf(ss), NORM_EPS);
    us4 o = {f2bf(v.x * inv), f2bf(v.y * inv), f2bf(v.z * inv), f2bf(v.w * inv)};
    *(us4*)&xn[row * Dv + lane * 4] = o;
    if (blockIdx.x < 64) lsum[blockIdx.x * 256 + threadIdx.x] = 0.f;
}

// ---------------------------------------------------------------------------
// 2) xT[b][d][n] = bf16(x[b][n][d])  (64x64 LDS tile transpose)
__global__ __launch_bounds__(256) void k_transpose(const float* __restrict__ x,
                                                   u16* __restrict__ xT) {
    __shared__ u16 tile[64][72];
    const int b = blockIdx.z;
    const int n0 = blockIdx.x * 64, d0 = blockIdx.y * 64;
    const int t = threadIdx.x;
#pragma unroll
    for (int it = 0; it < 4; ++it) {
        const int idx = it * 256 + t;
        const int nr = idx >> 4, c4 = (idx & 15) << 2;
        float4 v = *(const float4*)&x[((size_t)b * Nv + n0 + nr) * Dv + d0 + c4];
        tile[c4 + 0][nr] = f2bf(v.x);
        tile[c4 + 1][nr] = f2bf(v.y);
        tile[c4 + 2][nr] = f2bf(v.z);
        tile[c4 + 3][nr] = f2bf(v.w);
    }
    __syncthreads();
#pragma unroll
    for (int it = 0; it < 2; ++it) {
        const int idx = it * 256 + t;
        const int dr = idx >> 3, c8 = (idx & 7) << 3;
        us8 o = *(const us8*)&tile[dr][c8];
        *(us8*)&xT[((size_t)b * Dv + d0 + dr) * Nv + n0 + c8] = o;
    }
}

// ---------------------------------------------------------------------------
// 3) S = xn @ xn^T (bf16 MFMA, 128x128 tile, BK=64). Epilogue: store bf16 S,
//    atomically accumulate lsum[n] = sum_m exp(S[n,m]-1) (bf16-consistent).
__global__ __launch_bounds__(256) void k_gemm1(const u16* __restrict__ xn,
                                               u16* __restrict__ S,
                                               float* __restrict__ lsum) {
    __shared__ u16 As[128 * 64];
    __shared__ u16 Bs[128 * 64];
    const int b = blockIdx.z, bi = blockIdx.y, bj = blockIdx.x;
    const int t = threadIdx.x;
    const int wave = t >> 6, lane = t & 63;
    const int wr = wave >> 1, wc = wave & 1;
    const int l15 = lane & 15, kl = lane >> 4;
    const u16* xb = xn + (size_t)b * Nv * Dv;
    f32x4 acc[4][4] = {};
    for (int k0 = 0; k0 < Dv; k0 += 64) {
#pragma unroll
        for (int c = 0; c < 4; ++c) {
            const int off = c * 4096 + t * 16;
            const int row = off >> 7, sl = (off >> 4) & 7;
            gll16(xb + (size_t)(bi * 128 + row) * Dv + k0 + sl * 8,
                  (char*)As + c * 4096 + wave * 1024);
            gll16(xb + (size_t)(bj * 128 + row) * Dv + k0 + sl * 8,
                  (char*)Bs + c * 4096 + wave * 1024);
        }
        __syncthreads();
#pragma unroll
        for (int kk = 0; kk < 2; ++kk) {
            short8 av[4], bv[4];
#pragma unroll
            for (int i = 0; i < 4; ++i)
                av[i] = *(const short8*)&As[(wr * 64 + i * 16 + l15) * 64 + kk * 32 + kl * 8];
#pragma unroll
            for (int j = 0; j < 4; ++j)
                bv[j] = *(const short8*)&Bs[(wc * 64 + j * 16 + l15) * 64 + kk * 32 + kl * 8];
#pragma unroll
            for (int i = 0; i < 4; ++i)
#pragma unroll
                for (int j = 0; j < 4; ++j)
                    acc[i][j] = __builtin_amdgcn_mfma_f32_16x16x32_bf16(av[i], bv[j], acc[i][j], 0, 0, 0);
        }
        __syncthreads();
    }
    u16* Sb = S + (size_t)b * Nv * Nv;
#pragma unroll
    for (int i = 0; i < 4; ++i) {
        float rs[4] = {0.f, 0.f, 0.f, 0.f};
#pragma unroll
        for (int j = 0; j < 4; ++j) {
            const int col = bj * 128 + wc * 64 + j * 16 + l15;
#pragma unroll
            for (int r = 0; r < 4; ++r) {
                const int row = bi * 128 + wr * 64 + i * 16 + kl * 4 + r;
                const u16 hb = f2bf(acc[i][j][r]);
                Sb[(size_t)row * Nv + col] = hb;
                rs[r] += __expf(bf2f(hb) - 1.0f);
            }
        }
#pragma unroll
        for (int r = 0; r < 4; ++r) {
#pragma unroll
            for (int m = 1; m < 16; m <<= 1) rs[r] += __shfl_xor(rs[r], m, 64);
            if (l15 == 0)
                atomicAdd(&lsum[b * Nv + bi * 128 + wr * 64 + i * 16 + kl * 4 + r], rs[r]);
        }
    }
}

// ---------------------------------------------------------------------------
// 4) In-place dual-softmax weights: P[n,m] = exp(S[n,m]-1) * (1/l_n + 1/l_m).
//    (S symmetric, diag = 1 = row max, so this equals rowSM + colSM.)
__global__ __launch_bounds__(256) void k_dualw(u16* __restrict__ S,
                                               const float* __restrict__ lsum) {
    const int row = blockIdx.x;  // b*N + n
    const int b = row >> 11;
    u16* p = S + (size_t)row * Nv;
    const float cn = __builtin_amdgcn_rcpf(lsum[row]);
    const int m0 = threadIdx.x * 8;
    us8 sv = *(const us8*)&p[m0];
    const float* lb = lsum + (size_t)b * Nv;
    float4 la = *(const float4*)&lb[m0];
    float4 lc = *(const float4*)&lb[m0 + 4];
    float lm[8] = {la.x, la.y, la.z, la.w, lc.x, lc.y, lc.z, lc.w};
    us8 ov;
#pragma unroll
    for (int e = 0; e < 8; ++e) {
        const float s = bf2f((u16)sv[e]);
        const float w = __expf(s - 1.0f) * (cn + __builtin_amdgcn_rcpf(lm[e]));
        ov[e] = f2bf(w);
    }
    *(us8*)&p[m0] = ov;
}

// ---------------------------------------------------------------------------
// 5) x_neg = P @ x (bf16 MFMA via xT), fused epilogue:
//    out = LayerNorm(x - SCALE*x_neg) * gamma + beta.
//    Block: 64 rows x 256 cols (full D), 8 waves (2x4), wave tile 32x64.
__global__ __launch_bounds__(512) void k_gemm2ln(const u16* __restrict__ P,
                                                 const u16* __restrict__ xT,
                                                 const float* __restrict__ x,
                                                 const float* __restrict__ gamma,
                                                 const float* __restrict__ beta,
                                                 float* __restrict__ out) {
    __shared__ u16 Ps[64 * 64];
    __shared__ u16 Xs[256 * 64];
    __shared__ float red[64][4][2];
    const int b = blockIdx.y, bi = blockIdx.x;
    const int t = threadIdx.x;
    const int wave = t >> 6, lane = t & 63;
    const int wr = wave >> 2, wc = wave & 3;
    const int l15 = lane & 15, kl = lane >> 4;
    f32x4 acc[2][4] = {};
    const u16* Pb = P + ((size_t)b * Nv + bi * 64) * Nv;
    const u16* xTb = xT + (size_t)b * Dv * Nv;
    for (int k0 = 0; k0 < Nv; k0 += 64) {
        {
            const int off = t * 16;
            const int row = off >> 7, sl = (off >> 4) & 7;
            gll16(Pb + (size_t)row * Nv + k0 + sl * 8, (char*)Ps + wave * 1024);
        }
#pragma unroll
        for (int c = 0; c < 4; ++c) {
            const int off = c * 8192 + t * 16;
            const int row = off >> 7, sl = (off >> 4) & 7;
            gll16(xTb + (size_t)row * Nv + k0 + sl * 8,
                  (char*)Xs + c * 8192 + wave * 1024);
        }
        __syncthreads();
#pragma unroll
        for (int kk = 0; kk < 2; ++kk) {
            short8 av[2], bv[4];
            av[0] = *(const short8*)&Ps[(wr * 32 + l15) * 64 + kk * 32 + kl * 8];
            av[1] = *(const short8*)&Ps[(wr * 32 + 16 + l15) * 64 + kk * 32 + kl * 8];
#pragma unroll
            for (int j = 0; j < 4; ++j)
                bv[j] = *(const short8*)&Xs[(wc * 64 + j * 16 + l15) * 64 + kk * 32 + kl * 8];
#pragma unroll
            for (int i = 0; i < 2; ++i)
#pragma unroll
                for (int j = 0; j < 4; ++j)
                    acc[i][j] = __builtin_amdgcn_mfma_f32_16x16x32_bf16(av[i], bv[j], acc[i][j], 0, 0, 0);
        }
        __syncthreads();
    }
    // epilogue: t = x - SCALE*x_neg, LN across the 4 column-waves
    const float* xb = x + ((size_t)b * Nv + bi * 64) * Dv;
    float tv[2][4][4];
#pragma unroll
    for (int i = 0; i < 2; ++i) {
#pragma unroll
        for (int r = 0; r < 4; ++r) {
            const int rl = wr * 32 + i * 16 + kl * 4 + r;
            float s1 = 0.f, s2 = 0.f;
#pragma unroll
            for (int j = 0; j < 4; ++j) {
                const int cc = wc * 64 + j * 16 + l15;
                const float v = xb[(size_t)rl * Dv + cc] - SCALE * acc[i][j][r];
                tv[i][j][r] = v;
                s1 += v; s2 += v * v;
            }
#pragma unroll
            for (int m = 1; m < 16; m <<= 1) {
                s1 += __shfl_xor(s1, m, 64);
                s2 += __shfl_xor(s2, m, 64);
            }
            if (l15 == 0) { red[rl][wc][0] = s1; red[rl][wc][1] = s2; }
        }
    }
    __syncthreads();
#pragma unroll
    for (int i = 0; i < 2; ++i) {
#pragma unroll
        for (int r = 0; r < 4; ++r) {
            const int rl = wr * 32 + i * 16 + kl * 4 + r;
            const float s1 = red[rl][0][0] + red[rl][1][0] + red[rl][2][0] + red[rl][3][0];
            const float s2 = red[rl][0][1] + red[rl][1][1] + red[rl][2][1] + red[rl][3][1];
            const float mu = s1 * (1.0f / Dv);
            const float var = s2 * (1.0f / Dv) - mu * mu;
            const float rstd = rsqrtf(var + LN_EPS);
#pragma unroll
            for (int j = 0; j < 4; ++j) {
                const int cc = wc * 64 + j * 16 + l15;
                out[((size_t)b * Nv + bi * 64 + rl) * Dv + cc] =
                    (tv[i][j][r] - mu) * rstd * gamma[cc] + beta[cc];
            }
        }
    }
}

// ---------------------------------------------------------------------------
extern "C" void kernel_launch(void* const* d_in, const int* in_sizes, int n_in,
                              void* d_out, int out_size, void* d_ws, size_t ws_size,
                              hipStream_t stream) {
    const float* x = (const float*)d_in[0];
    const float* gamma = (const float*)d_in[1];
    const float* beta = (const float*)d_in[2];
    float* out = (float*)d_out;
    char* ws = (char*)d_ws;
    u16* xn = (u16*)ws;                       // 8 * 2048 * 256 * 2  = 8.39 MB
    u16* xT = (u16*)(ws + 8388608);           // 8.39 MB
    float* lsum = (float*)(ws + 16777216);    // 16384 * 4 = 64 KB
    u16* S = (u16*)(ws + 16842752);           // 8 * 2048 * 2048 * 2 = 67.1 MB

    k_prep<<<Bv * Nv / 4, 256, 0, stream>>>(x, xn, lsum);
    k_transpose<<<dim3(Nv / 64, Dv / 64, Bv), 256, 0, stream>>>(x, xT);
    k_gemm1<<<dim3(Nv / 128, Nv / 128, Bv), 256, 0, stream>>>(xn, S, lsum);
    k_dualw<<<Bv * Nv, 256, 0, stream>>>(S, lsum);
    k_gemm2ln<<<dim3(Nv / 64, Bv), 512, 0, stream>>>(S, xT, x, gamma, beta, out);
}

// Round 3
// 118.876 us; speedup vs baseline: 4.5720x; 1.1249x over previous
//
#include <hip/hip_runtime.h>
#include <hip/hip_bf16.h>

namespace {
constexpr int Bv = 8;
constexpr int Nv = 2048;
constexpr int Dv = 256;
constexpr float SCALE = 0.1f;
constexpr float LN_EPS = 1e-6f;
constexpr float NORM_EPS = 1e-12f;
}

typedef unsigned short u16;
typedef __attribute__((ext_vector_type(8))) short short8;
typedef __attribute__((ext_vector_type(4))) float f32x4;
typedef __attribute__((ext_vector_type(8))) unsigned short us8;
typedef __attribute__((ext_vector_type(4))) unsigned short us4;

__device__ __forceinline__ u16 f2bf(float f) {
    union { float f; unsigned u; } v; v.f = f;
    unsigned r = v.u + 0x7fffu + ((v.u >> 16) & 1u);
    return (u16)(r >> 16);
}
__device__ __forceinline__ float bf2f(u16 h) {
    union { unsigned u; float f; } v; v.u = ((unsigned)h) << 16; return v.f;
}
// global -> LDS direct DMA, 16B/lane. lds base must be wave-uniform; HW adds
// lane*16. Global address is per-lane (pre-swizzled source pattern, m173).
__device__ __forceinline__ void gll16(const void* g, void* l) {
    __builtin_amdgcn_global_load_lds(
        (__attribute__((address_space(1))) void*)(uintptr_t)g,
        (__attribute__((address_space(3))) void*)(uintptr_t)l, 16, 0, 0);
}
// Swizzled LDS read: tile rows are 64 bf16 = 128B = 8 slots of 16B.
// slot' = slot ^ (row&7)  (matches the staging-side source permutation).
__device__ __forceinline__ short8 lds_rd(const u16* base, int row, int slot) {
    return *(const short8*)((const char*)base + row * 128 + ((slot ^ (row & 7)) << 4));
}
__device__ __forceinline__ float wave_sum(float v) {
#pragma unroll
    for (int o = 1; o < 64; o <<= 1) v += __shfl_xor(v, o, 64);
    return v;
}

// ---------------------------------------------------------------------------
// 1) L2-normalize rows -> xn (bf16); also zero lsum.
__global__ __launch_bounds__(256) void k_prep(const float* __restrict__ x,
                                              u16* __restrict__ xn,
                                              float* __restrict__ lsum) {
    const int wave = threadIdx.x >> 6, lane = threadIdx.x & 63;
    const size_t row = (size_t)blockIdx.x * 4 + wave;
    float4 v = ((const float4*)(x + row * Dv))[lane];
    float ss = v.x * v.x + v.y * v.y + v.z * v.z + v.w * v.w;
    ss = wave_sum(ss);
    const float inv = 1.0f / fmaxf(sqrtf(ss), NORM_EPS);
    us4 o = {f2bf(v.x * inv), f2bf(v.y * inv), f2bf(v.z * inv), f2bf(v.w * inv)};
    *(us4*)&xn[row * Dv + lane * 4] = o;
    if (blockIdx.x < 64) lsum[blockIdx.x * 256 + threadIdx.x] = 0.f;
}

// ---------------------------------------------------------------------------
// 2) xT[b][d][n] = bf16(x[b][n][d])  (64x64 LDS tile transpose)
__global__ __launch_bounds__(256) void k_transpose(const float* __restrict__ x,
                                                   u16* __restrict__ xT) {
    __shared__ u16 tile[64][72];
    const int b = blockIdx.z;
    const int n0 = blockIdx.x * 64, d0 = blockIdx.y * 64;
    const int t = threadIdx.x;
#pragma unroll
    for (int it = 0; it < 4; ++it) {
        const int idx = it * 256 + t;
        const int nr = idx >> 4, c4 = (idx & 15) << 2;
        float4 v = *(const float4*)&x[((size_t)b * Nv + n0 + nr) * Dv + d0 + c4];
        tile[c4 + 0][nr] = f2bf(v.x);
        tile[c4 + 1][nr] = f2bf(v.y);
        tile[c4 + 2][nr] = f2bf(v.z);
        tile[c4 + 3][nr] = f2bf(v.w);
    }
    __syncthreads();
#pragma unroll
    for (int it = 0; it < 2; ++it) {
        const int idx = it * 256 + t;
        const int dr = idx >> 3, c8 = (idx & 7) << 3;
        us8 o = *(const us8*)&tile[dr][c8];
        *(us8*)&xT[((size_t)b * Dv + d0 + dr) * Nv + n0 + c8] = o;
    }
}

// ---------------------------------------------------------------------------
// 3) S = xn @ xn^T (bf16 MFMA, 128x128 tile, BK=64, swizzled LDS, 2-phase
//    dbuf). Epilogue: bf16 S + lsum[n] = sum_m exp(S[n,m]-1).
__global__ __launch_bounds__(256) void k_gemm1(const u16* __restrict__ xn,
                                               u16* __restrict__ S,
                                               float* __restrict__ lsum) {
    __shared__ u16 As[2][128 * 64];
    __shared__ u16 Bs[2][128 * 64];
    // XCD swizzle: 2048 wgs, 8 XCDs -> each XCD owns one batch b.
    const int wg = blockIdx.x;
    const int swz = (wg & 7) * 256 + (wg >> 3);
    const int b = swz >> 8, bi = (swz >> 4) & 15, bj = swz & 15;
    const int t = threadIdx.x;
    const int wave = t >> 6, lane = t & 63;
    const int wr = wave >> 1, wc = wave & 1;
    const int l15 = lane & 15, kl = lane >> 4;
    const int lrow = lane >> 3;             // 0..7 (row within wave's 8-row strip)
    const int sg = (lane & 7) ^ lrow;       // pre-swizzled global slot
    const u16* xb = xn + (size_t)b * Nv * Dv;

    auto stage = [&](int buf, int k0) {
#pragma unroll
        for (int c = 0; c < 4; ++c) {
            const int row = c * 32 + wave * 8 + lrow;
            gll16(xb + (size_t)(bi * 128 + row) * Dv + k0 + sg * 8,
                  (char*)As[buf] + c * 4096 + wave * 1024);
            gll16(xb + (size_t)(bj * 128 + row) * Dv + k0 + sg * 8,
                  (char*)Bs[buf] + c * 4096 + wave * 1024);
        }
    };

    f32x4 acc[4][4] = {};
    stage(0, 0);
    __syncthreads();
    int cur = 0;
    for (int kt = 0; kt < 4; ++kt) {
        if (kt < 3) stage(cur ^ 1, (kt + 1) * 64);
#pragma unroll
        for (int kk = 0; kk < 2; ++kk) {
            const int slot = kk * 4 + kl;
            short8 av[4], bv[4];
#pragma unroll
            for (int i = 0; i < 4; ++i)
                av[i] = lds_rd(As[cur], wr * 64 + i * 16 + l15, slot);
#pragma unroll
            for (int j = 0; j < 4; ++j)
                bv[j] = lds_rd(Bs[cur], wc * 64 + j * 16 + l15, slot);
#pragma unroll
            for (int i = 0; i < 4; ++i)
#pragma unroll
                for (int j = 0; j < 4; ++j)
                    acc[i][j] = __builtin_amdgcn_mfma_f32_16x16x32_bf16(av[i], bv[j], acc[i][j], 0, 0, 0);
        }
        __syncthreads();
        cur ^= 1;
    }
    u16* Sb = S + (size_t)b * Nv * Nv;
#pragma unroll
    for (int i = 0; i < 4; ++i) {
        float rs[4] = {0.f, 0.f, 0.f, 0.f};
#pragma unroll
        for (int j = 0; j < 4; ++j) {
            const int col = bj * 128 + wc * 64 + j * 16 + l15;
#pragma unroll
            for (int r = 0; r < 4; ++r) {
                const int row = bi * 128 + wr * 64 + i * 16 + kl * 4 + r;
                const u16 hb = f2bf(acc[i][j][r]);
                Sb[(size_t)row * Nv + col] = hb;
                rs[r] += __expf(bf2f(hb) - 1.0f);
            }
        }
#pragma unroll
        for (int r = 0; r < 4; ++r) {
#pragma unroll
            for (int m = 1; m < 16; m <<= 1) rs[r] += __shfl_xor(rs[r], m, 64);
            if (l15 == 0)
                atomicAdd(&lsum[b * Nv + bi * 128 + wr * 64 + i * 16 + kl * 4 + r], rs[r]);
        }
    }
}

// ---------------------------------------------------------------------------
// 4) In-place dual-softmax weights: P[n,m] = exp(S[n,m]-1) * (1/l_n + 1/l_m).
__global__ __launch_bounds__(256) void k_dualw(u16* __restrict__ S,
                                               const float* __restrict__ lsum) {
    const int row = blockIdx.x;  // b*N + n
    const int b = row >> 11;
    u16* p = S + (size_t)row * Nv;
    const float cn = __builtin_amdgcn_rcpf(lsum[row]);
    const int m0 = threadIdx.x * 8;
    us8 sv = *(const us8*)&p[m0];
    const float* lb = lsum + (size_t)b * Nv;
    float4 la = *(const float4*)&lb[m0];
    float4 lc = *(const float4*)&lb[m0 + 4];
    float lm[8] = {la.x, la.y, la.z, la.w, lc.x, lc.y, lc.z, lc.w};
    us8 ov;
#pragma unroll
    for (int e = 0; e < 8; ++e) {
        const float s = bf2f((u16)sv[e]);
        const float w = __expf(s - 1.0f) * (cn + __builtin_amdgcn_rcpf(lm[e]));
        ov[e] = f2bf(w);
    }
    *(us8*)&p[m0] = ov;
}

// ---------------------------------------------------------------------------
// 5) x_neg = P @ x (bf16 MFMA via xT, swizzled LDS, 2-phase dbuf), fused LN.
//    Block: 64 rows x 256 cols, 8 waves (2x4), wave tile 32x64.
__global__ __launch_bounds__(512) void k_gemm2ln(const u16* __restrict__ P,
                                                 const u16* __restrict__ xT,
                                                 const float* __restrict__ x,
                                                 const float* __restrict__ gamma,
                                                 const float* __restrict__ beta,
                                                 float* __restrict__ out) {
    __shared__ u16 Ps[2][64 * 64];    // 16 KB
    __shared__ u16 Xs[2][256 * 64];   // 64 KB  -> 80 KB total, 2 blocks/CU
    // XCD swizzle: 256 wgs -> each XCD owns one batch b (xT slice L2-resident).
    const int wg = blockIdx.x;
    const int swz = (wg & 7) * 32 + (wg >> 3);
    const int b = swz >> 5, bi = swz & 31;
    const int t = threadIdx.x;
    const int wave = t >> 6, lane = t & 63;
    const int wr = wave >> 2, wc = wave & 3;
    const int l15 = lane & 15, kl = lane >> 4;
    const int lrow = lane >> 3;
    const int sg = (lane & 7) ^ lrow;
    const u16* Pb = P + ((size_t)b * Nv + bi * 64) * Nv;
    const u16* xTb = xT + (size_t)b * Dv * Nv;

    auto stage = [&](int buf, int k0) {
        {
            const int row = wave * 8 + lrow;          // 0..63
            gll16(Pb + (size_t)row * Nv + k0 + sg * 8, (char*)Ps[buf] + wave * 1024);
        }
#pragma unroll
        for (int c = 0; c < 4; ++c) {
            const int row = c * 64 + wave * 8 + lrow; // 0..255 (d index)
            gll16(xTb + (size_t)row * Nv + k0 + sg * 8,
                  (char*)Xs[buf] + c * 8192 + wave * 1024);
        }
    };

    f32x4 acc[2][4] = {};
    stage(0, 0);
    __syncthreads();
    int cur = 0;
    for (int kt = 0; kt < 32; ++kt) {
        if (kt < 31) stage(cur ^ 1, (kt + 1) * 64);
#pragma unroll
        for (int kk = 0; kk < 2; ++kk) {
            const int slot = kk * 4 + kl;
            short8 av[2], bv[4];
            av[0] = lds_rd(Ps[cur], wr * 32 + l15, slot);
            av[1] = lds_rd(Ps[cur], wr * 32 + 16 + l15, slot);
#pragma unroll
            for (int j = 0; j < 4; ++j)
                bv[j] = lds_rd(Xs[cur], wc * 64 + j * 16 + l15, slot);
#pragma unroll
            for (int i = 0; i < 2; ++i)
#pragma unroll
                for (int j = 0; j < 4; ++j)
                    acc[i][j] = __builtin_amdgcn_mfma_f32_16x16x32_bf16(av[i], bv[j], acc[i][j], 0, 0, 0);
        }
        __syncthreads();
        cur ^= 1;
    }
    // epilogue: t = x - SCALE*x_neg, LN across the 4 column-waves.
    // red[] overlaid on Ps (dead after final barrier above).
    float (*red)[4][2] = (float (*)[4][2])(void*)Ps;
    const float* xb = x + ((size_t)b * Nv + bi * 64) * Dv;
    float tv[2][4][4];
#pragma unroll
    for (int i = 0; i < 2; ++i) {
#pragma unroll
        for (int r = 0; r < 4; ++r) {
            const int rl = wr * 32 + i * 16 + kl * 4 + r;
            float s1 = 0.f, s2 = 0.f;
#pragma unroll
            for (int j = 0; j < 4; ++j) {
                const int cc = wc * 64 + j * 16 + l15;
                const float v = xb[(size_t)rl * Dv + cc] - SCALE * acc[i][j][r];
                tv[i][j][r] = v;
                s1 += v; s2 += v * v;
            }
#pragma unroll
            for (int m = 1; m < 16; m <<= 1) {
                s1 += __shfl_xor(s1, m, 64);
                s2 += __shfl_xor(s2, m, 64);
            }
            if (l15 == 0) { red[rl][wc][0] = s1; red[rl][wc][1] = s2; }
        }
    }
    __syncthreads();
#pragma unroll
    for (int i = 0; i < 2; ++i) {
#pragma unroll
        for (int r = 0; r < 4; ++r) {
            const int rl = wr * 32 + i * 16 + kl * 4 + r;
            const float s1 = red[rl][0][0] + red[rl][1][0] + red[rl][2][0] + red[rl][3][0];
            const float s2 = red[rl][0][1] + red[rl][1][1] + red[rl][2][1] + red[rl][3][1];
            const float mu = s1 * (1.0f / Dv);
            const float var = s2 * (1.0f / Dv) - mu * mu;
            const float rstd = rsqrtf(var + LN_EPS);
#pragma unroll
            for (int j = 0; j < 4; ++j) {
                const int cc = wc * 64 + j * 16 + l15;
                out[((size_t)b * Nv + bi * 64 + rl) * Dv + cc] =
                    (tv[i][j][r] - mu) * rstd * gamma[cc] + beta[cc];
            }
        }
    }
}

// ---------------------------------------------------------------------------
extern "C" void kernel_launch(void* const* d_in, const int* in_sizes, int n_in,
                              void* d_out, int out_size, void* d_ws, size_t ws_size,
                              hipStream_t stream) {
    const float* x = (const float*)d_in[0];
    const float* gamma = (const float*)d_in[1];
    const float* beta = (const float*)d_in[2];
    float* out = (float*)d_out;
    char* ws = (char*)d_ws;
    u16* xn = (u16*)ws;                       // 8.39 MB
    u16* xT = (u16*)(ws + 8388608);           // 8.39 MB
    float* lsum = (float*)(ws + 16777216);    // 64 KB
    u16* S = (u16*)(ws + 16842752);           // 67.1 MB

    k_prep<<<Bv * Nv / 4, 256, 0, stream>>>(x, xn, lsum);
    k_transpose<<<dim3(Nv / 64, Dv / 64, Bv), 256, 0, stream>>>(x, xT);
    k_gemm1<<<Bv * (Nv / 128) * (Nv / 128), 256, 0, stream>>>(xn, S, lsum);
    k_dualw<<<Bv * Nv, 256, 0, stream>>>(S, lsum);
    k_gemm2ln<<<Bv * (Nv / 64), 512, 0, stream>>>(S, xT, x, gamma, beta, out);
}

// Round 4
// 114.299 us; speedup vs baseline: 4.7551x; 1.0400x over previous
//
#include <hip/hip_runtime.h>
#include <hip/hip_bf16.h>

namespace {
constexpr int Bv = 8;
constexpr int Nv = 2048;
constexpr int Dv = 256;
constexpr float SCALE = 0.1f;
constexpr float LN_EPS = 1e-6f;
constexpr float NORM_EPS = 1e-12f;
}

typedef unsigned short u16;
typedef __attribute__((ext_vector_type(8))) short short8;
typedef __attribute__((ext_vector_type(4))) float f32x4;
typedef __attribute__((ext_vector_type(8))) unsigned short us8;
typedef __attribute__((ext_vector_type(4))) unsigned short us4;

__device__ __forceinline__ u16 f2bf(float f) {
    union { float f; unsigned u; } v; v.f = f;
    unsigned r = v.u + 0x7fffu + ((v.u >> 16) & 1u);
    return (u16)(r >> 16);
}
__device__ __forceinline__ float bf2f(u16 h) {
    union { unsigned u; float f; } v; v.u = ((unsigned)h) << 16; return v.f;
}
// global -> LDS direct DMA, 16B/lane. lds base wave-uniform; HW adds lane*16.
__device__ __forceinline__ void gll16(const void* g, void* l) {
    __builtin_amdgcn_global_load_lds(
        (__attribute__((address_space(1))) void*)(uintptr_t)g,
        (__attribute__((address_space(3))) void*)(uintptr_t)l, 16, 0, 0);
}
// Swizzled LDS read: rows are 64 bf16 = 128B = 8 slots of 16B.
// slot' = slot ^ (row&7)  (matches the staging-side source permutation).
__device__ __forceinline__ short8 lds_rd(const u16* base, int row, int slot) {
    return *(const short8*)((const char*)base + row * 128 + ((slot ^ (row & 7)) << 4));
}
__device__ __forceinline__ float wave_sum(float v) {
#pragma unroll
    for (int o = 1; o < 64; o <<= 1) v += __shfl_xor(v, o, 64);
    return v;
}

// ---------------------------------------------------------------------------
// 1) L2-normalize rows -> xn (bf16); also zero lsum.
__global__ __launch_bounds__(256) void k_prep(const float* __restrict__ x,
                                              u16* __restrict__ xn,
                                              float* __restrict__ lsum) {
    const int wave = threadIdx.x >> 6, lane = threadIdx.x & 63;
    const size_t row = (size_t)blockIdx.x * 4 + wave;
    float4 v = ((const float4*)(x + row * Dv))[lane];
    float ss = v.x * v.x + v.y * v.y + v.z * v.z + v.w * v.w;
    ss = wave_sum(ss);
    const float inv = 1.0f / fmaxf(sqrtf(ss), NORM_EPS);
    us4 o = {f2bf(v.x * inv), f2bf(v.y * inv), f2bf(v.z * inv), f2bf(v.w * inv)};
    *(us4*)&xn[row * Dv + lane * 4] = o;
    if (blockIdx.x < 64) lsum[blockIdx.x * 256 + threadIdx.x] = 0.f;
}

// ---------------------------------------------------------------------------
// 2) xT[b][d][n] = bf16(x[b][n][d])  (64x64 LDS tile transpose)
__global__ __launch_bounds__(256) void k_transpose(const float* __restrict__ x,
                                                   u16* __restrict__ xT) {
    __shared__ u16 tile[64][72];
    const int b = blockIdx.z;
    const int n0 = blockIdx.x * 64, d0 = blockIdx.y * 64;
    const int t = threadIdx.x;
#pragma unroll
    for (int it = 0; it < 4; ++it) {
        const int idx = it * 256 + t;
        const int nr = idx >> 4, c4 = (idx & 15) << 2;
        float4 v = *(const float4*)&x[((size_t)b * Nv + n0 + nr) * Dv + d0 + c4];
        tile[c4 + 0][nr] = f2bf(v.x);
        tile[c4 + 1][nr] = f2bf(v.y);
        tile[c4 + 2][nr] = f2bf(v.z);
        tile[c4 + 3][nr] = f2bf(v.w);
    }
    __syncthreads();
#pragma unroll
    for (int it = 0; it < 2; ++it) {
        const int idx = it * 256 + t;
        const int dr = idx >> 3, c8 = (idx & 7) << 3;
        us8 o = *(const us8*)&tile[dr][c8];
        *(us8*)&xT[((size_t)b * Dv + d0 + dr) * Nv + n0 + c8] = o;
    }
}

// ---------------------------------------------------------------------------
// 3) E = exp(xn @ xn^T - 1) stored bf16 (128x128 tile, BK=64, swizzled LDS,
//    2-phase dbuf). lsum[n] += row-sums (f32, atomics). Vectorized store via
//    LDS restage into the dead staging buffers.
__global__ __launch_bounds__(256) void k_gemm1(const u16* __restrict__ xn,
                                               u16* __restrict__ E,
                                               float* __restrict__ lsum) {
    __shared__ u16 lds4[4][128 * 64];   // As0,As1,Bs0,Bs1 ; epilogue: [128][136]
    const int wg = blockIdx.x;
    const int swz = (wg & 7) * 256 + (wg >> 3);   // XCD owns one batch
    const int b = swz >> 8, bi = (swz >> 4) & 15, bj = swz & 15;
    const int t = threadIdx.x;
    const int wave = t >> 6, lane = t & 63;
    const int wr = wave >> 1, wc = wave & 1;
    const int l15 = lane & 15, kl = lane >> 4;
    const int lrow = lane >> 3;
    const int sg = (lane & 7) ^ lrow;   // pre-swizzled global slot
    const u16* xb = xn + (size_t)b * Nv * Dv;

    auto stage = [&](int buf, int k0) {
#pragma unroll
        for (int c = 0; c < 4; ++c) {
            const int row = c * 32 + wave * 8 + lrow;
            gll16(xb + (size_t)(bi * 128 + row) * Dv + k0 + sg * 8,
                  (char*)lds4[buf] + c * 4096 + wave * 1024);
            gll16(xb + (size_t)(bj * 128 + row) * Dv + k0 + sg * 8,
                  (char*)lds4[2 + buf] + c * 4096 + wave * 1024);
        }
    };

    f32x4 acc[4][4] = {};
    stage(0, 0);
    __syncthreads();
    int cur = 0;
    for (int kt = 0; kt < 4; ++kt) {
        if (kt < 3) stage(cur ^ 1, (kt + 1) * 64);
#pragma unroll
        for (int kk = 0; kk < 2; ++kk) {
            const int slot = kk * 4 + kl;
            short8 av[4], bv[4];
#pragma unroll
            for (int i = 0; i < 4; ++i)
                av[i] = lds_rd(lds4[cur], wr * 64 + i * 16 + l15, slot);
#pragma unroll
            for (int j = 0; j < 4; ++j)
                bv[j] = lds_rd(lds4[2 + cur], wc * 64 + j * 16 + l15, slot);
#pragma unroll
            for (int i = 0; i < 4; ++i)
#pragma unroll
                for (int j = 0; j < 4; ++j)
                    acc[i][j] = __builtin_amdgcn_mfma_f32_16x16x32_bf16(av[i], bv[j], acc[i][j], 0, 0, 0);
        }
        __syncthreads();
        cur ^= 1;
    }
    // epilogue: e = exp(s-1) (f32), row-sum -> atomic lsum, bf16 tile -> LDS.
    u16* Et = &lds4[0][0];   // [128][136] u16 = 34.8 KB (staging bufs dead)
#pragma unroll
    for (int i = 0; i < 4; ++i) {
        float rs[4] = {0.f, 0.f, 0.f, 0.f};
#pragma unroll
        for (int j = 0; j < 4; ++j) {
#pragma unroll
            for (int r = 0; r < 4; ++r) {
                const float e = __expf(acc[i][j][r] - 1.0f);
                rs[r] += e;
                Et[(wr * 64 + i * 16 + kl * 4 + r) * 136 + wc * 64 + j * 16 + l15] = f2bf(e);
            }
        }
#pragma unroll
        for (int r = 0; r < 4; ++r) {
#pragma unroll
            for (int m = 1; m < 16; m <<= 1) rs[r] += __shfl_xor(rs[r], m, 64);
            if (l15 == 0)
                atomicAdd(&lsum[b * Nv + bi * 128 + wr * 64 + i * 16 + kl * 4 + r], rs[r]);
        }
    }
    __syncthreads();
    u16* Ebl = E + (size_t)b * Nv * Nv;
    const int rr = t >> 1, hh = t & 1;   // 2 threads/row, 8 chunks of 8 u16
#pragma unroll
    for (int c = 0; c < 8; ++c) {
        const int colb = c * 16 + hh * 8;
        *(us8*)&Ebl[(size_t)(bi * 128 + rr) * Nv + bj * 128 + colb] =
            *(const us8*)&Et[rr * 136 + colb];
    }
}

// ---------------------------------------------------------------------------
// 4) x_neg = P @ x where P[n,m] = E[n,m]*(1/l_n + 1/l_m), applied on the fly
//    during A-tile reg-staging (T14 async split). B = xT via gll16.
//    Fused epilogue: out = LayerNorm(x - SCALE*x_neg)*gamma + beta.
//    Block: 64 rows x 256 cols, 8 waves (2x4), wave tile 32x64.
__global__ __launch_bounds__(512) void k_gemm2ln(const u16* __restrict__ E,
                                                 const float* __restrict__ lsum,
                                                 const u16* __restrict__ xT,
                                                 const float* __restrict__ x,
                                                 const float* __restrict__ gamma,
                                                 const float* __restrict__ beta,
                                                 float* __restrict__ out) {
    __shared__ u16 Ps[2][64 * 64];    // 16 KB
    __shared__ u16 Xs[2][256 * 64];   // 64 KB -> 80 KB total, 2 blocks/CU
    const int wg = blockIdx.x;
    const int swz = (wg & 7) * 32 + (wg >> 3);   // XCD owns one batch
    const int b = swz >> 5, bi = swz & 31;
    const int t = threadIdx.x;
    const int wave = t >> 6, lane = t & 63;
    const int wr = wave >> 2, wc = wave & 3;
    const int l15 = lane & 15, kl = lane >> 4;
    const int lrow = lane >> 3;
    const int sg = (lane & 7) ^ lrow;   // Xs gll16 pre-swizzled source slot
    const int s8 = lane & 7;
    const int srow = wave * 8 + lrow;   // A-tile row this thread stages (0..63)
    const float* lsb = lsum + (size_t)b * Nv;
    const u16* Erow = E + ((size_t)b * Nv + bi * 64 + srow) * Nv;
    const u16* xTb = xT + (size_t)b * Dv * Nv;
    const float linv_n = __builtin_amdgcn_rcpf(lsb[bi * 64 + srow]);
    char* const pswb = (char*)0 + srow * 128 + ((s8 ^ (srow & 7)) << 4);

    auto issueX = [&](int buf, int k0) {
#pragma unroll
        for (int c = 0; c < 4; ++c) {
            const int row = c * 64 + wave * 8 + lrow;
            gll16(xTb + (size_t)row * Nv + k0 + sg * 8,
                  (char*)Xs[buf] + c * 8192 + wave * 1024);
        }
    };
    auto weightStore = [&](int buf, us8 ev, float4 l0, float4 l1) {
        float lm[8] = {l0.x, l0.y, l0.z, l0.w, l1.x, l1.y, l1.z, l1.w};
        us8 w;
#pragma unroll
        for (int e = 0; e < 8; ++e)
            w[e] = f2bf(bf2f((u16)ev[e]) * (linv_n + __builtin_amdgcn_rcpf(lm[e])));
        *(us8*)((char*)Ps[buf] + (size_t)(pswb - (char*)0)) = w;
    };

    f32x4 acc[2][4] = {};
    issueX(0, 0);
    {
        us8 ev0 = *(const us8*)&Erow[s8 * 8];
        float4 a0 = *(const float4*)&lsb[s8 * 8];
        float4 a1 = *(const float4*)&lsb[s8 * 8 + 4];
        weightStore(0, ev0, a0, a1);
    }
    __syncthreads();
    int cur = 0;
    us8 ev;
    float4 l0, l1;
    for (int kt = 0; kt < 32; ++kt) {
        const int k1 = (kt + 1) * 64;
        if (kt < 31) {
            issueX(cur ^ 1, k1);                       // async -> LDS
            ev = *(const us8*)&Erow[k1 + s8 * 8];      // issue early (T14)
            l0 = *(const float4*)&lsb[k1 + s8 * 8];
            l1 = *(const float4*)&lsb[k1 + s8 * 8 + 4];
        }
#pragma unroll
        for (int kk = 0; kk < 2; ++kk) {
            const int slot = kk * 4 + kl;
            short8 av[2], bv[4];
            av[0] = lds_rd(Ps[cur], wr * 32 + l15, slot);
            av[1] = lds_rd(Ps[cur], wr * 32 + 16 + l15, slot);
#pragma unroll
            for (int j = 0; j < 4; ++j)
                bv[j] = lds_rd(Xs[cur], wc * 64 + j * 16 + l15, slot);
#pragma unroll
            for (int i = 0; i < 2; ++i)
#pragma unroll
                for (int j = 0; j < 4; ++j)
                    acc[i][j] = __builtin_amdgcn_mfma_f32_16x16x32_bf16(av[i], bv[j], acc[i][j], 0, 0, 0);
        }
        if (kt < 31) weightStore(cur ^ 1, ev, l0, l1);  // write late (T14)
        __syncthreads();
        cur ^= 1;
    }
    // epilogue: t = x - SCALE*x_neg, LN across the 4 column-waves.
    float (*red)[4][2] = (float (*)[4][2])(void*)Ps;   // overlay on dead Ps
    const float* xb = x + ((size_t)b * Nv + bi * 64) * Dv;
    float tv[2][4][4];
#pragma unroll
    for (int i = 0; i < 2; ++i) {
#pragma unroll
        for (int r = 0; r < 4; ++r) {
            const int rl = wr * 32 + i * 16 + kl * 4 + r;
            float s1 = 0.f, s2 = 0.f;
#pragma unroll
            for (int j = 0; j < 4; ++j) {
                const int cc = wc * 64 + j * 16 + l15;
                const float v = xb[(size_t)rl * Dv + cc] - SCALE * acc[i][j][r];
                tv[i][j][r] = v;
                s1 += v; s2 += v * v;
            }
#pragma unroll
            for (int m = 1; m < 16; m <<= 1) {
                s1 += __shfl_xor(s1, m, 64);
                s2 += __shfl_xor(s2, m, 64);
            }
            if (l15 == 0) { red[rl][wc][0] = s1; red[rl][wc][1] = s2; }
        }
    }
    __syncthreads();
#pragma unroll
    for (int i = 0; i < 2; ++i) {
#pragma unroll
        for (int r = 0; r < 4; ++r) {
            const int rl = wr * 32 + i * 16 + kl * 4 + r;
            const float s1 = red[rl][0][0] + red[rl][1][0] + red[rl][2][0] + red[rl][3][0];
            const float s2 = red[rl][0][1] + red[rl][1][1] + red[rl][2][1] + red[rl][3][1];
            const float mu = s1 * (1.0f / Dv);
            const float var = s2 * (1.0f / Dv) - mu * mu;
            const float rstd = rsqrtf(var + LN_EPS);
#pragma unroll
            for (int j = 0; j < 4; ++j) {
                const int cc = wc * 64 + j * 16 + l15;
                out[((size_t)b * Nv + bi * 64 + rl) * Dv + cc] =
                    (tv[i][j][r] - mu) * rstd * gamma[cc] + beta[cc];
            }
        }
    }
}

// ---------------------------------------------------------------------------
extern "C" void kernel_launch(void* const* d_in, const int* in_sizes, int n_in,
                              void* d_out, int out_size, void* d_ws, size_t ws_size,
                              hipStream_t stream) {
    const float* x = (const float*)d_in[0];
    const float* gamma = (const float*)d_in[1];
    const float* beta = (const float*)d_in[2];
    float* out = (float*)d_out;
    char* ws = (char*)d_ws;
    u16* xn = (u16*)ws;                       // 8.39 MB
    u16* xT = (u16*)(ws + 8388608);           // 8.39 MB
    float* lsum = (float*)(ws + 16777216);    // 64 KB
    u16* E = (u16*)(ws + 16842752);           // 67.1 MB

    k_prep<<<Bv * Nv / 4, 256, 0, stream>>>(x, xn, lsum);
    k_transpose<<<dim3(Nv / 64, Dv / 64, Bv), 256, 0, stream>>>(x, xT);
    k_gemm1<<<Bv * (Nv / 128) * (Nv / 128), 256, 0, stream>>>(xn, E, lsum);
    k_gemm2ln<<<Bv * (Nv / 64), 512, 0, stream>>>(E, lsum, xT, x, gamma, beta, out);
}

// Round 5
// 106.303 us; speedup vs baseline: 5.1128x; 1.0752x over previous
//
#include <hip/hip_runtime.h>
#include <hip/hip_bf16.h>

namespace {
constexpr int Bv = 8;
constexpr int Nv = 2048;
constexpr int Dv = 256;
constexpr float SCALE = 0.1f;
constexpr float LN_EPS = 1e-6f;
constexpr float NORM_EPS = 1e-12f;
}

typedef unsigned short u16;
typedef __attribute__((ext_vector_type(8))) short short8;
typedef __attribute__((ext_vector_type(4))) float f32x4;
typedef __attribute__((ext_vector_type(8))) unsigned short us8;
typedef __attribute__((ext_vector_type(4))) unsigned short us4;

__device__ __forceinline__ u16 f2bf(float f) {
    union { float f; unsigned u; } v; v.f = f;
    unsigned r = v.u + 0x7fffu + ((v.u >> 16) & 1u);
    return (u16)(r >> 16);
}
__device__ __forceinline__ float bf2f(u16 h) {
    union { unsigned u; float f; } v; v.u = ((unsigned)h) << 16; return v.f;
}
// global -> LDS direct DMA, 16B/lane. lds base wave-uniform; HW adds lane*16.
__device__ __forceinline__ void gll16(const void* g, void* l) {
    __builtin_amdgcn_global_load_lds(
        (__attribute__((address_space(1))) void*)(uintptr_t)g,
        (__attribute__((address_space(3))) void*)(uintptr_t)l, 16, 0, 0);
}
// Swizzled LDS read: rows are 64 bf16 = 128B = 8 slots of 16B.
// slot' = slot ^ (row&7)  (matches the staging-side source permutation).
__device__ __forceinline__ short8 lds_rd(const u16* base, int row, int slot) {
    return *(const short8*)((const char*)base + row * 128 + ((slot ^ (row & 7)) << 4));
}
__device__ __forceinline__ float wave_sum(float v) {
#pragma unroll
    for (int o = 1; o < 64; o <<= 1) v += __shfl_xor(v, o, 64);
    return v;
}

// ---------------------------------------------------------------------------
// 1) L2-normalize rows -> xn (bf16); also zero lsum.
__global__ __launch_bounds__(256) void k_prep(const float* __restrict__ x,
                                              u16* __restrict__ xn,
                                              float* __restrict__ lsum) {
    const int wave = threadIdx.x >> 6, lane = threadIdx.x & 63;
    const size_t row = (size_t)blockIdx.x * 4 + wave;
    float4 v = ((const float4*)(x + row * Dv))[lane];
    float ss = v.x * v.x + v.y * v.y + v.z * v.z + v.w * v.w;
    ss = wave_sum(ss);
    const float inv = 1.0f / fmaxf(sqrtf(ss), NORM_EPS);
    us4 o = {f2bf(v.x * inv), f2bf(v.y * inv), f2bf(v.z * inv), f2bf(v.w * inv)};
    *(us4*)&xn[row * Dv + lane * 4] = o;
    if (blockIdx.x < 64) lsum[blockIdx.x * 256 + threadIdx.x] = 0.f;
}

// ---------------------------------------------------------------------------
// 2) xT[b][d][n] = bf16(x[b][n][d])  (64x64 LDS tile transpose)
__global__ __launch_bounds__(256) void k_transpose(const float* __restrict__ x,
                                                   u16* __restrict__ xT) {
    __shared__ u16 tile[64][72];
    const int b = blockIdx.z;
    const int n0 = blockIdx.x * 64, d0 = blockIdx.y * 64;
    const int t = threadIdx.x;
#pragma unroll
    for (int it = 0; it < 4; ++it) {
        const int idx = it * 256 + t;
        const int nr = idx >> 4, c4 = (idx & 15) << 2;
        float4 v = *(const float4*)&x[((size_t)b * Nv + n0 + nr) * Dv + d0 + c4];
        tile[c4 + 0][nr] = f2bf(v.x);
        tile[c4 + 1][nr] = f2bf(v.y);
        tile[c4 + 2][nr] = f2bf(v.z);
        tile[c4 + 3][nr] = f2bf(v.w);
    }
    __syncthreads();
#pragma unroll
    for (int it = 0; it < 2; ++it) {
        const int idx = it * 256 + t;
        const int dr = idx >> 3, c8 = (idx & 7) << 3;
        us8 o = *(const us8*)&tile[dr][c8];
        *(us8*)&xT[((size_t)b * Dv + d0 + dr) * Nv + n0 + c8] = o;
    }
}

// ---------------------------------------------------------------------------
// 3) E = exp(xn @ xn^T - 1) stored bf16 (128x128 tile, BK=64, swizzled LDS,
//    2-phase dbuf). lsum[n] += row-sums (f32, atomics). Store restaged via
//    LDS so each 16-lane group writes a 256B-contiguous row chunk.
__global__ __launch_bounds__(256) void k_gemm1(const u16* __restrict__ xn,
                                               u16* __restrict__ E,
                                               float* __restrict__ lsum) {
    __shared__ u16 lds4[4][128 * 64];   // As0,As1,Bs0,Bs1 ; epilogue: [128][136]
    const int wg = blockIdx.x;
    const int swz = (wg & 7) * 256 + (wg >> 3);   // XCD owns one batch
    const int b = swz >> 8, bi = (swz >> 4) & 15, bj = swz & 15;
    const int t = threadIdx.x;
    const int wave = t >> 6, lane = t & 63;
    const int wr = wave >> 1, wc = wave & 1;
    const int l15 = lane & 15, kl = lane >> 4;
    const int lrow = lane >> 3;
    const int sg = (lane & 7) ^ lrow;   // pre-swizzled global slot
    const u16* xb = xn + (size_t)b * Nv * Dv;

    auto stage = [&](int buf, int k0) {
#pragma unroll
        for (int c = 0; c < 4; ++c) {
            const int row = c * 32 + wave * 8 + lrow;
            gll16(xb + (size_t)(bi * 128 + row) * Dv + k0 + sg * 8,
                  (char*)lds4[buf] + c * 4096 + wave * 1024);
            gll16(xb + (size_t)(bj * 128 + row) * Dv + k0 + sg * 8,
                  (char*)lds4[2 + buf] + c * 4096 + wave * 1024);
        }
    };

    f32x4 acc[4][4] = {};
    stage(0, 0);
    __syncthreads();
    int cur = 0;
    for (int kt = 0; kt < 4; ++kt) {
        if (kt < 3) stage(cur ^ 1, (kt + 1) * 64);
#pragma unroll
        for (int kk = 0; kk < 2; ++kk) {
            const int slot = kk * 4 + kl;
            short8 av[4], bv[4];
#pragma unroll
            for (int i = 0; i < 4; ++i)
                av[i] = lds_rd(lds4[cur], wr * 64 + i * 16 + l15, slot);
#pragma unroll
            for (int j = 0; j < 4; ++j)
                bv[j] = lds_rd(lds4[2 + cur], wc * 64 + j * 16 + l15, slot);
#pragma unroll
            for (int i = 0; i < 4; ++i)
#pragma unroll
                for (int j = 0; j < 4; ++j)
                    acc[i][j] = __builtin_amdgcn_mfma_f32_16x16x32_bf16(av[i], bv[j], acc[i][j], 0, 0, 0);
        }
        __syncthreads();
        cur ^= 1;
    }
    // epilogue: e = exp(s-1) (f32), row-sum -> atomic lsum, bf16 tile -> LDS.
    u16* Et = &lds4[0][0];   // [128][136] u16 = 34.8 KB (staging bufs dead)
#pragma unroll
    for (int i = 0; i < 4; ++i) {
        float rs[4] = {0.f, 0.f, 0.f, 0.f};
#pragma unroll
        for (int j = 0; j < 4; ++j) {
#pragma unroll
            for (int r = 0; r < 4; ++r) {
                const float e = __expf(acc[i][j][r] - 1.0f);
                rs[r] += e;
                Et[(wr * 64 + i * 16 + kl * 4 + r) * 136 + wc * 64 + j * 16 + l15] = f2bf(e);
            }
        }
#pragma unroll
        for (int r = 0; r < 4; ++r) {
#pragma unroll
            for (int m = 1; m < 16; m <<= 1) rs[r] += __shfl_xor(rs[r], m, 64);
            if (l15 == 0)
                atomicAdd(&lsum[b * Nv + bi * 128 + wr * 64 + i * 16 + kl * 4 + r], rs[r]);
        }
    }
    __syncthreads();
    // Coalesced store: 16 lanes cover one row's 128 cols = 256B contiguous.
    u16* Ebl = E + (size_t)b * Nv * Nv;
    const int rr16 = t >> 4, l16 = t & 15;
#pragma unroll
    for (int p = 0; p < 8; ++p) {
        const int row = p * 16 + rr16;
        *(us8*)&Ebl[(size_t)(bi * 128 + row) * Nv + bj * 128 + l16 * 8] =
            *(const us8*)&Et[row * 136 + l16 * 8];
    }
}

// ---------------------------------------------------------------------------
// 4) x_neg = P @ x where P[n,m] = E[n,m]*(1/l_n + 1/l_m), applied during
//    A-tile reg-staging (depth-2 prefetch). B = xT via gll16. Fused LN.
//    Block: 32 rows x 256 cols, 8 waves (1x8), wave tile 32x32. 2 blocks/CU.
__global__ __launch_bounds__(512) void k_gemm2ln(const u16* __restrict__ E,
                                                 const float* __restrict__ lsum,
                                                 const u16* __restrict__ xT,
                                                 const float* __restrict__ x,
                                                 const float* __restrict__ gamma,
                                                 const float* __restrict__ beta,
                                                 float* __restrict__ out) {
    __shared__ u16 Ps[2][32 * 64];    // 8 KB
    __shared__ u16 Xs[2][256 * 64];   // 64 KB -> 72 KB total, 2 blocks/CU
    const int wg = blockIdx.x;        // 512 wgs
    const int swz = (wg & 7) * 64 + (wg >> 3);   // XCD owns one batch
    const int b = swz >> 6, bi = swz & 63;       // 32-row tile index
    const int t = threadIdx.x;
    const int wave = t >> 6, lane = t & 63;
    const int l15 = lane & 15, kl = lane >> 4;
    const int lrow = lane >> 3;
    const int sg = (lane & 7) ^ lrow;   // Xs gll16 pre-swizzled source slot
    const int s8 = lane & 7;
    const int srow = (wave * 8 + lrow) & 31;   // A-tile row (waves 0-3 stage)
    const float* lsb = lsum + (size_t)b * Nv;
    const u16* Erow = E + ((size_t)b * Nv + bi * 32 + srow) * Nv;
    const u16* xTb = xT + (size_t)b * Dv * Nv;
    const float linv_n = __builtin_amdgcn_rcpf(lsb[bi * 32 + srow]);
    const int pswb = srow * 128 + ((s8 ^ (srow & 7)) << 4);

    auto issueX = [&](int buf, int k0) {
#pragma unroll
        for (int c = 0; c < 4; ++c) {
            const int row = c * 64 + wave * 8 + lrow;
            gll16(xTb + (size_t)row * Nv + k0 + sg * 8,
                  (char*)Xs[buf] + c * 8192 + wave * 1024);
        }
    };
    auto weightStore = [&](int buf, us8 ev, float4 l0, float4 l1) {
        float lm[8] = {l0.x, l0.y, l0.z, l0.w, l1.x, l1.y, l1.z, l1.w};
        us8 w;
#pragma unroll
        for (int e = 0; e < 8; ++e)
            w[e] = f2bf(bf2f((u16)ev[e]) * (linv_n + __builtin_amdgcn_rcpf(lm[e])));
        *(us8*)((char*)Ps[buf] + pswb) = w;
    };

    f32x4 acc[2][2] = {};
    issueX(0, 0);
    us8 ev{};
    float4 l0{}, l1{};
    if (wave < 4) {
        ev = *(const us8*)&Erow[s8 * 8];
        l0 = *(const float4*)&lsb[s8 * 8];
        l1 = *(const float4*)&lsb[s8 * 8 + 4];
        weightStore(0, ev, l0, l1);
        ev = *(const us8*)&Erow[64 + s8 * 8];       // depth-2: tile 1 in flight
        l0 = *(const float4*)&lsb[64 + s8 * 8];
        l1 = *(const float4*)&lsb[64 + s8 * 8 + 4];
    }
    __syncthreads();
    int cur = 0;
    for (int kt = 0; kt < 32; ++kt) {
        if (kt < 31) issueX(cur ^ 1, (kt + 1) * 64);
#pragma unroll
        for (int kk = 0; kk < 2; ++kk) {
            const int slot = kk * 4 + kl;
            short8 av[2], bv[2];
            av[0] = lds_rd(Ps[cur], l15, slot);
            av[1] = lds_rd(Ps[cur], 16 + l15, slot);
            bv[0] = lds_rd(Xs[cur], wave * 32 + l15, slot);
            bv[1] = lds_rd(Xs[cur], wave * 32 + 16 + l15, slot);
#pragma unroll
            for (int i = 0; i < 2; ++i)
#pragma unroll
                for (int j = 0; j < 2; ++j)
                    acc[i][j] = __builtin_amdgcn_mfma_f32_16x16x32_bf16(av[i], bv[j], acc[i][j], 0, 0, 0);
        }
        if (kt < 31 && wave < 4) {
            weightStore(cur ^ 1, ev, l0, l1);       // w for tile kt+1
            if (kt < 30) {
                const int k2 = (kt + 2) * 64;       // issue tile kt+2 (depth-2)
                ev = *(const us8*)&Erow[k2 + s8 * 8];
                l0 = *(const float4*)&lsb[k2 + s8 * 8];
                l1 = *(const float4*)&lsb[k2 + s8 * 8 + 4];
            }
        }
        __syncthreads();
        cur ^= 1;
    }
    // epilogue: t = x - SCALE*x_neg, LN across the 8 column-waves.
    float (*red)[8][2] = (float (*)[8][2])(void*)Ps;   // overlay on dead Ps
    const float* xb = x + ((size_t)b * Nv + bi * 32) * Dv;
    float tv[2][2][4];
#pragma unroll
    for (int i = 0; i < 2; ++i) {
#pragma unroll
        for (int r = 0; r < 4; ++r) {
            const int rl = i * 16 + kl * 4 + r;
            float s1 = 0.f, s2 = 0.f;
#pragma unroll
            for (int j = 0; j < 2; ++j) {
                const int cc = wave * 32 + j * 16 + l15;
                const float v = xb[(size_t)rl * Dv + cc] - SCALE * acc[i][j][r];
                tv[i][j][r] = v;
                s1 += v; s2 += v * v;
            }
#pragma unroll
            for (int m = 1; m < 16; m <<= 1) {
                s1 += __shfl_xor(s1, m, 64);
                s2 += __shfl_xor(s2, m, 64);
            }
            if (l15 == 0) { red[rl][wave][0] = s1; red[rl][wave][1] = s2; }
        }
    }
    __syncthreads();
#pragma unroll
    for (int i = 0; i < 2; ++i) {
#pragma unroll
        for (int r = 0; r < 4; ++r) {
            const int rl = i * 16 + kl * 4 + r;
            float s1 = 0.f, s2 = 0.f;
#pragma unroll
            for (int w = 0; w < 8; ++w) { s1 += red[rl][w][0]; s2 += red[rl][w][1]; }
            const float mu = s1 * (1.0f / Dv);
            const float var = s2 * (1.0f / Dv) - mu * mu;
            const float rstd = rsqrtf(var + LN_EPS);
#pragma unroll
            for (int j = 0; j < 2; ++j) {
                const int cc = wave * 32 + j * 16 + l15;
                out[((size_t)b * Nv + bi * 32 + rl) * Dv + cc] =
                    (tv[i][j][r] - mu) * rstd * gamma[cc] + beta[cc];
            }
        }
    }
}

// ---------------------------------------------------------------------------
extern "C" void kernel_launch(void* const* d_in, const int* in_sizes, int n_in,
                              void* d_out, int out_size, void* d_ws, size_t ws_size,
                              hipStream_t stream) {
    const float* x = (const float*)d_in[0];
    const float* gamma = (const float*)d_in[1];
    const float* beta = (const float*)d_in[2];
    float* out = (float*)d_out;
    char* ws = (char*)d_ws;
    u16* xn = (u16*)ws;                       // 8.39 MB
    u16* xT = (u16*)(ws + 8388608);           // 8.39 MB
    float* lsum = (float*)(ws + 16777216);    // 64 KB
    u16* E = (u16*)(ws + 16842752);           // 67.1 MB

    k_prep<<<Bv * Nv / 4, 256, 0, stream>>>(x, xn, lsum);
    k_transpose<<<dim3(Nv / 64, Dv / 64, Bv), 256, 0, stream>>>(x, xT);
    k_gemm1<<<Bv * (Nv / 128) * (Nv / 128), 256, 0, stream>>>(xn, E, lsum);
    k_gemm2ln<<<Bv * (Nv / 32), 512, 0, stream>>>(E, lsum, xT, x, gamma, beta, out);
}

// Round 6
// 85.639 us; speedup vs baseline: 6.3465x; 1.2413x over previous
//
#include <hip/hip_runtime.h>
#include <hip/hip_bf16.h>

namespace {
constexpr int Bv = 8;
constexpr int Nv = 2048;
constexpr int Dv = 256;
constexpr float SCALE = 0.1f;
constexpr float LN_EPS = 1e-6f;
constexpr float NORM_EPS = 1e-12f;
}

typedef unsigned short u16;
typedef unsigned char u8;
typedef __attribute__((ext_vector_type(8))) short short8;
typedef __attribute__((ext_vector_type(4))) float f32x4;
typedef __attribute__((ext_vector_type(8))) unsigned short us8;
typedef __attribute__((ext_vector_type(4))) unsigned short us4;

__device__ __forceinline__ u16 f2bf(float f) {
    union { float f; unsigned u; } v; v.f = f;
    unsigned r = v.u + 0x7fffu + ((v.u >> 16) & 1u);
    return (u16)(r >> 16);
}
__device__ __forceinline__ float bf2f(u16 h) {
    union { unsigned u; float f; } v; v.u = ((unsigned)h) << 16; return v.f;
}
// global -> LDS direct DMA, 16B/lane. lds base wave-uniform; HW adds lane*16.
__device__ __forceinline__ void gll16(const void* g, void* l) {
    __builtin_amdgcn_global_load_lds(
        (__attribute__((address_space(1))) void*)(uintptr_t)g,
        (__attribute__((address_space(3))) void*)(uintptr_t)l, 16, 0, 0);
}
// Swizzled LDS read: rows are 64 bf16 = 128B = 8 slots of 16B.
// slot' = slot ^ (row&7)  (matches the staging-side source permutation).
__device__ __forceinline__ short8 lds_rd(const void* base, int row, int slot) {
    return *(const short8*)((const char*)base + row * 128 + ((slot ^ (row & 7)) << 4));
}
__device__ __forceinline__ float wave_sum(float v) {
#pragma unroll
    for (int o = 1; o < 64; o <<= 1) v += __shfl_xor(v, o, 64);
    return v;
}

// ---------------------------------------------------------------------------
// 1) L2-normalize rows -> xn (bf16); also zero lsum.
__global__ __launch_bounds__(256) void k_prep(const float* __restrict__ x,
                                              u16* __restrict__ xn,
                                              float* __restrict__ lsum) {
    const int wave = threadIdx.x >> 6, lane = threadIdx.x & 63;
    const size_t row = (size_t)blockIdx.x * 4 + wave;
    float4 v = ((const float4*)(x + row * Dv))[lane];
    float ss = v.x * v.x + v.y * v.y + v.z * v.z + v.w * v.w;
    ss = wave_sum(ss);
    const float inv = 1.0f / fmaxf(sqrtf(ss), NORM_EPS);
    us4 o = {f2bf(v.x * inv), f2bf(v.y * inv), f2bf(v.z * inv), f2bf(v.w * inv)};
    *(us4*)&xn[row * Dv + lane * 4] = o;
    if (blockIdx.x < 64) lsum[blockIdx.x * 256 + threadIdx.x] = 0.f;
}

// ---------------------------------------------------------------------------
// 2) xT[b][d][n] = bf16(x[b][n][d])  (64x64 LDS tile transpose)
__global__ __launch_bounds__(256) void k_transpose(const float* __restrict__ x,
                                                   u16* __restrict__ xT) {
    __shared__ u16 tile[64][72];
    const int b = blockIdx.z;
    const int n0 = blockIdx.x * 64, d0 = blockIdx.y * 64;
    const int t = threadIdx.x;
#pragma unroll
    for (int it = 0; it < 4; ++it) {
        const int idx = it * 256 + t;
        const int nr = idx >> 4, c4 = (idx & 15) << 2;
        float4 v = *(const float4*)&x[((size_t)b * Nv + n0 + nr) * Dv + d0 + c4];
        tile[c4 + 0][nr] = f2bf(v.x);
        tile[c4 + 1][nr] = f2bf(v.y);
        tile[c4 + 2][nr] = f2bf(v.z);
        tile[c4 + 3][nr] = f2bf(v.w);
    }
    __syncthreads();
#pragma unroll
    for (int it = 0; it < 2; ++it) {
        const int idx = it * 256 + t;
        const int dr = idx >> 3, c8 = (idx & 7) << 3;
        us8 o = *(const us8*)&tile[dr][c8];
        *(us8*)&xT[((size_t)b * Dv + d0 + dr) * Nv + n0 + c8] = o;
    }
}

// ---------------------------------------------------------------------------
// 3) E = exp(xn @ xn^T - 1) stored fp8-e4m3 (256x256 tile, BK=64, swizzled
//    LDS, 2-phase dbuf). lsum[n] += f32 row-sums (atomics). Since E is
//    symmetric, the tile is stored TRANSPOSED at the mirrored location: LDS
//    restage is column-major so acc r-quads pack into single ds_write_b32,
//    and global stores stay 256B-contiguous.
__global__ __launch_bounds__(512, 2) void k_gemm1(const u16* __restrict__ xn,
                                                  u8* __restrict__ E,
                                                  float* __restrict__ lsum) {
    __shared__ char smem[131072];   // As0|As1|Bs0|Bs1 (32KB each); epi: fp8 tile
    const int wg = blockIdx.x;      // 512 wgs: XCD owns one batch
    const int swz = (wg & 7) * 64 + (wg >> 3);
    const int b = swz >> 6, bi = (swz >> 3) & 7, bj = swz & 7;
    const int t = threadIdx.x;
    const int wave = t >> 6, lane = t & 63;
    const int wr = wave >> 2, wc = wave & 3;    // 2 x 4 waves, tile 128x64
    const int l15 = lane & 15, kl = lane >> 4;
    const int lrow = lane >> 3;
    const int sg = (lane & 7) ^ lrow;           // pre-swizzled global slot
    const u16* xb = xn + (size_t)b * Nv * Dv;

    auto stage = [&](int buf, int k0) {
        char* da = smem + buf * 32768;
        char* db = smem + 65536 + buf * 32768;
#pragma unroll
        for (int c = 0; c < 4; ++c) {
            const int row = c * 64 + wave * 8 + lrow;
            gll16(xb + (size_t)(bi * 256 + row) * Dv + k0 + sg * 8,
                  da + c * 8192 + wave * 1024);
            gll16(xb + (size_t)(bj * 256 + row) * Dv + k0 + sg * 8,
                  db + c * 8192 + wave * 1024);
        }
    };

    f32x4 acc[8][4] = {};
    stage(0, 0);
    __syncthreads();
    int cur = 0;
    for (int kt = 0; kt < 4; ++kt) {
        if (kt < 3) stage(cur ^ 1, (kt + 1) * 64);
        const char* pa = smem + cur * 32768;
        const char* pb = smem + 65536 + cur * 32768;
#pragma unroll
        for (int kk = 0; kk < 2; ++kk) {
            const int slot = kk * 4 + kl;
            short8 bv[4];
#pragma unroll
            for (int j = 0; j < 4; ++j)
                bv[j] = lds_rd(pb, wc * 64 + j * 16 + l15, slot);
#pragma unroll
            for (int i = 0; i < 8; ++i) {
                short8 av = lds_rd(pa, wr * 128 + i * 16 + l15, slot);
#pragma unroll
                for (int j = 0; j < 4; ++j)
                    acc[i][j] = __builtin_amdgcn_mfma_f32_16x16x32_bf16(av, bv[j], acc[i][j], 0, 0, 0);
            }
        }
        __syncthreads();
        cur ^= 1;
    }
    // epilogue: e = exp(s-1), rowsum atomics, fp8 pack -> LDS [col][row] p272.
    u8* lds8 = (u8*)smem;
#pragma unroll
    for (int i = 0; i < 8; ++i) {
        float rs[4] = {0.f, 0.f, 0.f, 0.f};
#pragma unroll
        for (int j = 0; j < 4; ++j) {
            const int col = wc * 64 + j * 16 + l15;
            const float e0 = __expf(acc[i][j][0] - 1.0f);
            const float e1 = __expf(acc[i][j][1] - 1.0f);
            const float e2 = __expf(acc[i][j][2] - 1.0f);
            const float e3 = __expf(acc[i][j][3] - 1.0f);
            rs[0] += e0; rs[1] += e1; rs[2] += e2; rs[3] += e3;
            int w = __builtin_amdgcn_cvt_pk_fp8_f32(e0, e1, 0, false);
            w = __builtin_amdgcn_cvt_pk_fp8_f32(e2, e3, w, true);
            *(int*)&lds8[col * 272 + wr * 128 + i * 16 + kl * 4] = w;
        }
#pragma unroll
        for (int r = 0; r < 4; ++r) {
#pragma unroll
            for (int m = 1; m < 16; m <<= 1) rs[r] += __shfl_xor(rs[r], m, 64);
            if (l15 == 0)
                atomicAdd(&lsum[b * Nv + bi * 256 + wr * 128 + i * 16 + kl * 4 + r], rs[r]);
        }
    }
    __syncthreads();
    // store tile TRANSPOSED at mirrored location (valid: E symmetric).
    u8* Eb = E + (size_t)b * Nv * Nv;
    const int l16 = t & 15;
#pragma unroll
    for (int p = 0; p < 8; ++p) {
        const int c = p * 32 + (t >> 4);
        *(uint4*)&Eb[(size_t)(bj * 256 + c) * Nv + bi * 256 + l16 * 16] =
            *(const uint4*)&lds8[c * 272 + l16 * 16];
    }
}

// ---------------------------------------------------------------------------
// 4) x_neg = P @ x, P[n,m] = E[n,m]*(1/l_n + 1/l_m) applied during A-tile
//    reg-staging (fp8 E, depth-3 prefetch; 1/l cached in LDS). B = xT via
//    gll16. Fused epilogue: out = LayerNorm(x - SCALE*x_neg)*gamma + beta.
//    Block: 64 rows x 256 cols, 8 waves (2x4), wave tile 32x64.
__global__ __launch_bounds__(512) void k_gemm2ln(const u8* __restrict__ E,
                                                 const float* __restrict__ lsum,
                                                 const u16* __restrict__ xT,
                                                 const float* __restrict__ x,
                                                 const float* __restrict__ gamma,
                                                 const float* __restrict__ beta,
                                                 float* __restrict__ out) {
    __shared__ u16 Ps[2][64 * 64];    // 16 KB
    __shared__ u16 Xs[2][256 * 64];   // 64 KB
    __shared__ float rlv[Nv];         // 8 KB  (1/l_m)  -> 88 KB total
    const int wg = blockIdx.x;        // 256 wgs: XCD owns one batch
    const int swz = (wg & 7) * 32 + (wg >> 3);
    const int b = swz >> 5, bi = swz & 31;
    const int t = threadIdx.x;
    const int wave = t >> 6, lane = t & 63;
    const int wr = wave >> 2, wc = wave & 3;
    const int l15 = lane & 15, kl = lane >> 4;
    const int lrow = lane >> 3;
    const int sg = (lane & 7) ^ lrow;   // Xs gll16 pre-swizzled source slot
    const int s8 = lane & 7;
    const int srow = t >> 3;            // A-tile row this thread stages (0..63)
    const float* lsb = lsum + (size_t)b * Nv;
    const u8* Erow = E + ((size_t)b * Nv + bi * 64 + srow) * Nv;
    const u16* xTb = xT + (size_t)b * Dv * Nv;
    const int pswb = srow * 128 + ((s8 ^ (srow & 7)) << 4);

    // fill 1/l LDS table (4 per thread)
#pragma unroll
    for (int q = 0; q < 4; ++q) {
        const int m = q * 512 + t;
        rlv[m] = __builtin_amdgcn_rcpf(lsb[m]);
    }

    auto issueX = [&](int buf, int k0) {
#pragma unroll
        for (int c = 0; c < 4; ++c) {
            const int row = c * 64 + wave * 8 + lrow;
            gll16(xTb + (size_t)row * Nv + k0 + sg * 8,
                  (char*)Xs[buf] + c * 8192 + wave * 1024);
        }
    };

    issueX(0, 0);
    uint2 evB = *(const uint2*)(Erow + s8 * 8);
    __syncthreads();   // rlv ready (and Xs0 drained)
    const float linv_n = rlv[bi * 64 + srow];

    auto weightStore = [&](int buf, uint2 ev, int k0) {
        float4 ra = *(const float4*)&rlv[k0 + s8 * 8];
        float4 rb = *(const float4*)&rlv[k0 + s8 * 8 + 4];
        us8 o;
        o[0] = f2bf(__builtin_amdgcn_cvt_f32_fp8(ev.x, 0) * (linv_n + ra.x));
        o[1] = f2bf(__builtin_amdgcn_cvt_f32_fp8(ev.x, 1) * (linv_n + ra.y));
        o[2] = f2bf(__builtin_amdgcn_cvt_f32_fp8(ev.x, 2) * (linv_n + ra.z));
        o[3] = f2bf(__builtin_amdgcn_cvt_f32_fp8(ev.x, 3) * (linv_n + ra.w));
        o[4] = f2bf(__builtin_amdgcn_cvt_f32_fp8(ev.y, 0) * (linv_n + rb.x));
        o[5] = f2bf(__builtin_amdgcn_cvt_f32_fp8(ev.y, 1) * (linv_n + rb.y));
        o[6] = f2bf(__builtin_amdgcn_cvt_f32_fp8(ev.y, 2) * (linv_n + rb.z));
        o[7] = f2bf(__builtin_amdgcn_cvt_f32_fp8(ev.y, 3) * (linv_n + rb.w));
        *(us8*)((char*)Ps[buf] + pswb) = o;
    };

    weightStore(0, evB, 0);
    evB = *(const uint2*)(Erow + 64 + s8 * 8);
    uint2 evC = *(const uint2*)(Erow + 128 + s8 * 8);
    __syncthreads();   // Ps0 ready
    f32x4 acc[2][4] = {};
    int cur = 0;
    for (int kt = 0; kt < 32; ++kt) {
        const int k1 = (kt + 1) * 64;
        if (kt < 31) issueX(cur ^ 1, k1);
#pragma unroll
        for (int kk = 0; kk < 2; ++kk) {
            const int slot = kk * 4 + kl;
            short8 av[2], bv[4];
            av[0] = lds_rd(Ps[cur], wr * 32 + l15, slot);
            av[1] = lds_rd(Ps[cur], wr * 32 + 16 + l15, slot);
#pragma unroll
            for (int j = 0; j < 4; ++j)
                bv[j] = lds_rd(Xs[cur], wc * 64 + j * 16 + l15, slot);
#pragma unroll
            for (int i = 0; i < 2; ++i)
#pragma unroll
                for (int j = 0; j < 4; ++j)
                    acc[i][j] = __builtin_amdgcn_mfma_f32_16x16x32_bf16(av[i], bv[j], acc[i][j], 0, 0, 0);
        }
        if (kt < 31) {
            weightStore(cur ^ 1, evB, k1);
            evB = evC;
            if (kt <= 28) evC = *(const uint2*)(Erow + (kt + 3) * 64 + s8 * 8);
        }
        __syncthreads();
        cur ^= 1;
    }
    // epilogue: t = x - SCALE*x_neg, LN across the 4 column-waves.
    float (*red)[4][2] = (float (*)[4][2])(void*)Ps;   // overlay on dead Ps
    const float* xb = x + ((size_t)b * Nv + bi * 64) * Dv;
    float tv[2][4][4];
#pragma unroll
    for (int i = 0; i < 2; ++i) {
#pragma unroll
        for (int r = 0; r < 4; ++r) {
            const int rr = wr * 32 + i * 16 + kl * 4 + r;
            float s1 = 0.f, s2 = 0.f;
#pragma unroll
            for (int j = 0; j < 4; ++j) {
                const int cc = wc * 64 + j * 16 + l15;
                const float v = xb[(size_t)rr * Dv + cc] - SCALE * acc[i][j][r];
                tv[i][j][r] = v;
                s1 += v; s2 += v * v;
            }
#pragma unroll
            for (int m = 1; m < 16; m <<= 1) {
                s1 += __shfl_xor(s1, m, 64);
                s2 += __shfl_xor(s2, m, 64);
            }
            if (l15 == 0) { red[rr][wc][0] = s1; red[rr][wc][1] = s2; }
        }
    }
    __syncthreads();
#pragma unroll
    for (int i = 0; i < 2; ++i) {
#pragma unroll
        for (int r = 0; r < 4; ++r) {
            const int rr = wr * 32 + i * 16 + kl * 4 + r;
            const float s1 = red[rr][0][0] + red[rr][1][0] + red[rr][2][0] + red[rr][3][0];
            const float s2 = red[rr][0][1] + red[rr][1][1] + red[rr][2][1] + red[rr][3][1];
            const float mu = s1 * (1.0f / Dv);
            const float var = s2 * (1.0f / Dv) - mu * mu;
            const float rstd = rsqrtf(var + LN_EPS);
#pragma unroll
            for (int j = 0; j < 4; ++j) {
                const int cc = wc * 64 + j * 16 + l15;
                out[((size_t)b * Nv + bi * 64 + rr) * Dv + cc] =
                    (tv[i][j][r] - mu) * rstd * gamma[cc] + beta[cc];
            }
        }
    }
}

// ---------------------------------------------------------------------------
extern "C" void kernel_launch(void* const* d_in, const int* in_sizes, int n_in,
                              void* d_out, int out_size, void* d_ws, size_t ws_size,
                              hipStream_t stream) {
    const float* x = (const float*)d_in[0];
    const float* gamma = (const float*)d_in[1];
    const float* beta = (const float*)d_in[2];
    float* out = (float*)d_out;
    char* ws = (char*)d_ws;
    u16* xn = (u16*)ws;                       // 8.39 MB
    u16* xT = (u16*)(ws + 8388608);           // 8.39 MB
    float* lsum = (float*)(ws + 16777216);    // 64 KB
    u8* E = (u8*)(ws + 16842752);             // 33.5 MB (fp8)

    k_prep<<<Bv * Nv / 4, 256, 0, stream>>>(x, xn, lsum);
    k_transpose<<<dim3(Nv / 64, Dv / 64, Bv), 256, 0, stream>>>(x, xT);
    k_gemm1<<<Bv * (Nv / 256) * (Nv / 256), 512, 0, stream>>>(xn, E, lsum);
    k_gemm2ln<<<Bv * (Nv / 64), 512, 0, stream>>>(E, lsum, xT, x, gamma, beta, out);
}